// Round 3
// baseline (1058.050 us; speedup 1.0000x reference)
//
#include <hip/hip_runtime.h>
#include <cstdint>
#include <cstddef>

// LSTM B=256,S=512,C=64,H=128, 2 layers, gates i,f,g,o (torch order).
// Round 6: merged MFMA phase. Round-5 ledger (2850 cy/step): LDS pipe
// ~1150 cy (96 ds_read_b128/CU/step), EW VALU ~800 cy/SIMD, MFMA 465 cy/SIMD,
// mostly serialized by barrier-locked phases. This round:
//   1. L0-hh and L1-ih share ONE h0 fragment read (they read identical
//      addresses in round 5): per kk, h0f feeds 8 independent MFMAs.
//      12 -> 8 ds_read_b128/wave/step (-33% LDS pipe load).
//   2. EW-L0 placed after the h1 kk-loop in source: its VALU/trans chain is
//      independent of the h1-hh MFMAs -> compiler co-issues them.
//   3. Everything else from round 5 kept: asm-pinned register/AGPR-resident
//      weights (48 B-frags), broadcast-redirect A reads, 1 lgkm-only
//      barrier/step, xg prefetch spanning the barrier.
// Risk watch: a0+a1 now co-live (+16 VGPR peak). If spills reappear
// (round-4 pathology: dur ~900+, FETCH +12MB), revert to split phases.
//
// MFMA 16x16x32 bf16 frags (verified rounds 1-5):
//   A[m=lane&15][k=(lane>>4)*8+j], B == W[n=lane&15][k] 16B row chunk,
//   D[m=4*(lane>>4)+reg][n=lane&15]
// Batch rows permuted into tile rows {m : (m&3)<2}: elementwise touches
// rr=0,1 only (2 rows/lane); batch row of tile row m is 2*(m>>2)+(m&1).

#define S_LEN 512
#define B_SZ  256
#define C_IN  64
#define HDIM  128
#define XG_TSTRIDE (32 * 512 * 8)   // shorts per timestep slot of xg

using short8  = __attribute__((ext_vector_type(8))) short;   // 8 bf16
using float4v = __attribute__((ext_vector_type(4))) float;

template<bool V> struct Flag { static constexpr bool value = V; };

__device__ __forceinline__ unsigned short f2b(float f) {
    union { float f; unsigned int u; } v; v.f = f;
    unsigned int u = v.u;
    return (unsigned short)((u + 0x7FFFu + ((u >> 16) & 1u)) >> 16);
}
__device__ __forceinline__ float b2f(unsigned short s) {
    union { unsigned int u; float f; } v; v.u = ((unsigned int)s) << 16;
    return v.f;
}
// lean activations: sigma = rcp(1+exp2(-x*log2e)), tanh = 1-2*rcp(1+exp2(2x*log2e))
__device__ __forceinline__ float sig_(float x) {
    return __builtin_amdgcn_rcpf(1.0f + __builtin_amdgcn_exp2f(x * -1.442695041f));
}
__device__ __forceinline__ float tanh_(float x) {
    return 1.0f - 2.0f * __builtin_amdgcn_rcpf(1.0f + __builtin_amdgcn_exp2f(x * 2.885390082f));
}
__device__ __forceinline__ short8 load8_f2b(const float* s) {
    const float4v f0 = *(const float4v*)s;
    const float4v f1 = *(const float4v*)(s + 4);
    short8 t;
#pragma unroll
    for (int e = 0; e < 4; ++e) {
        t[e]     = (short)f2b(f0[e]);
        t[e + 4] = (short)f2b(f1[e]);
    }
    return t;
}

// ---- weight conversion (fp32 -> bf16 B-frag-readable row-major) ----
__global__ void conv_kernel(const float* __restrict__ whh0,
                            const float* __restrict__ wih1, const float* __restrict__ whh1,
                            const float* __restrict__ bih1, const float* __restrict__ bhh1,
                            unsigned short* __restrict__ whh0_b, unsigned short* __restrict__ wih1_b,
                            unsigned short* __restrict__ whh1_b, float* __restrict__ bias1) {
    int i = blockIdx.x * blockDim.x + threadIdx.x;
    if (i < 4 * HDIM * HDIM) {
        whh0_b[i] = f2b(whh0[i]);
        wih1_b[i] = f2b(wih1[i]);
        whh1_b[i] = f2b(whh1[i]);
    }
    if (i < 4 * HDIM) bias1[i] = bih1[i] + bhh1[i];
}

// ---- hoisted L0 input GEMM: xg[t][blk][tid][8] = (x@Wih0^T + bih0 + bhh0),
//      packed per-lane in D-layout order [g*2+rr] so the recurrent kernel's
//      lane (same blk,tid mapping) loads its 8 acc-init values as one 16B read.
__global__ __launch_bounds__(512, 2)
void xg_gemm(const float* __restrict__ x, const float* __restrict__ wih0,
             const float* __restrict__ bih0, const float* __restrict__ bhh0,
             unsigned short* __restrict__ xg) {
    const int tid = threadIdx.x;
    const int w = tid >> 6, L = tid & 63, q = L >> 4, r = L & 15;
    const int blk = blockIdx.x, tch = blockIdx.y;
    const int boff = blk * 8, j = w * 16 + r;
    const int rowload = (r >> 2) * 2 + (r & 1);

    short8 wf[4][2]; float bias_s[4];
#pragma unroll
    for (int g = 0; g < 4; ++g) {
        const int nrow = g * HDIM + j;
#pragma unroll
        for (int kk = 0; kk < 2; ++kk)
            wf[g][kk] = load8_f2b(wih0 + (size_t)nrow * C_IN + kk * 32 + q * 8);
        bias_s[g] = bih0[nrow] + bhh0[nrow];
    }

    const float* px = x + ((size_t)(boff + rowload) * S_LEN + (size_t)tch * 32) * C_IN + q * 8;
    unsigned short* po = xg + ((size_t)(tch * 32) * 32 + blk) * 4096 + (size_t)tid * 8;

    for (int tt = 0; tt < 32; ++tt) {
        short8 xa[2];
#pragma unroll
        for (int kk = 0; kk < 2; ++kk) xa[kk] = load8_f2b(px + kk * 32);
        float4v a[4];
#pragma unroll
        for (int g = 0; g < 4; ++g) a[g] = (float4v){bias_s[g], bias_s[g], 0.f, 0.f};
#pragma unroll
        for (int kk = 0; kk < 2; ++kk)
#pragma unroll
            for (int g = 0; g < 4; ++g)
                a[g] = __builtin_amdgcn_mfma_f32_16x16x32_bf16(xa[kk], wf[g][kk], a[g], 0, 0, 0);
        short8 o;
#pragma unroll
        for (int g = 0; g < 4; ++g) {
            o[2 * g]     = (short)f2b(a[g][0]);
            o[2 * g + 1] = (short)f2b(a[g][1]);
        }
        *(short8*)po = o;
        px += C_IN;
        po += XG_TSTRIDE;
    }
}

// ---- fused 2-layer recurrence ----
__global__ __launch_bounds__(512, 2)
void lstm_fused(const unsigned short* __restrict__ whh0_b,
                const unsigned short* __restrict__ wih1_b,
                const unsigned short* __restrict__ whh1_b,
                const float* __restrict__ bias1,
                const unsigned short* __restrict__ xg,
                float* __restrict__ out) {
    // LDS: h0 double-buffer + h1 double-buffer, each 2048 shorts (16 rows x 128 cols)
    __shared__ __align__(16) unsigned short hbuf[4 * 2048];
    const int tid = threadIdx.x;
    const int w = tid >> 6, L = tid & 63, q = L >> 4, r = L & 15;
    const int blk = blockIdx.x;
    const int boff = blk * 8, j = w * 16 + r;

    // register/AGPR-resident weights: 48 B-frags = 192 regs, pinned vs remat
    short8 whh0[4][4], wih1[4][4], whh1[4][4];
    float b1s[4];
#pragma unroll
    for (int g = 0; g < 4; ++g) {
        const size_t nrow = (size_t)(g * HDIM + j);
#pragma unroll
        for (int kk = 0; kk < 4; ++kk) {
            whh0[g][kk] = *(const short8*)(whh0_b + nrow * HDIM + kk * 32 + q * 8);
            wih1[g][kk] = *(const short8*)(wih1_b + nrow * HDIM + kk * 32 + q * 8);
            whh1[g][kk] = *(const short8*)(whh1_b + nrow * HDIM + kk * 32 + q * 8);
        }
        b1s[g] = bias1[g * HDIM + j];
    }
#pragma unroll
    for (int g = 0; g < 4; ++g) {
        asm volatile("" : "+v"(whh0[g][0]), "+v"(whh0[g][1]), "+v"(whh0[g][2]), "+v"(whh0[g][3]));
        asm volatile("" : "+v"(wih1[g][0]), "+v"(wih1[g][1]), "+v"(wih1[g][2]), "+v"(wih1[g][3]));
        asm volatile("" : "+v"(whh1[g][0]), "+v"(whh1[g][1]), "+v"(whh1[g][2]), "+v"(whh1[g][3]));
    }

    for (int idx = tid; idx < 4 * 1024; idx += 512) ((unsigned int*)hbuf)[idx] = 0u;

    float cf0[2] = {0.f, 0.f}, cf1[2] = {0.f, 0.f};
    // A-frag read: don't-care rows ((r&3)>=2) redirect to the valid row two
    // below -> same-address broadcast, halves unique LDS dwords.
    const int rred = ((r & 3) < 2) ? r : (r - 2);
    const int rdoff = q * 128 + rred * 8;               // + kk*512 per K-chunk
    const int chunkbase = (j >> 3) * 128 + (j & 7);     // h write slot (col-chunk layout)
    float* fout = out + (size_t)(boff + 2 * q) * HDIM + j;

    const unsigned short* pxg = xg + (size_t)blk * 4096 + (size_t)tid * 8;
    short8 xgA = *(const short8*)pxg;   // xg[t=0]
    pxg += XG_TSTRIDE;
    short8 xgB;

    __syncthreads();    // covers LDS zero + weight/xg load drain (once, cold)

    // iteration k: L0 h0_k (if D0) and L1 h1_{k-1} (if D1); both read only
    // previous-iteration buffers r0/r1, write w0/w1. One barrier at the end.
    auto step = [&](auto D0_, auto D1_, auto FIN_,
                    unsigned short* r0, unsigned short* w0,
                    unsigned short* r1, unsigned short* w1,
                    short8& xc, short8& xn) {
        constexpr bool D0  = decltype(D0_)::value;
        constexpr bool D1  = decltype(D1_)::value;
        constexpr bool FIN = decltype(FIN_)::value;

        if constexpr (!FIN) {            // prefetch next xg (vmcnt load, spans the barrier)
            xn = *(const short8*)pxg;
            pxg += XG_TSTRIDE;
        }

        float4v a0[4], a1[4];
        if constexpr (D0) {
#pragma unroll
            for (int g = 0; g < 4; ++g)
                a0[g] = (float4v){b2f((unsigned short)xc[2 * g]),
                                  b2f((unsigned short)xc[2 * g + 1]), 0.f, 0.f};
        }
        if constexpr (D1) {
#pragma unroll
            for (int g = 0; g < 4; ++g) a1[g] = (float4v){b1s[g], b1s[g], 0.f, 0.f};
        }

        // shared h0 K-loop: each h0f fragment feeds L0-hh AND L1-ih
        // (8 independent MFMAs per ds_read_b128)
#pragma unroll
        for (int kk = 0; kk < 4; ++kk) {
            const short8 h0f = *(const short8*)(r0 + kk * 512 + rdoff);
            if constexpr (D0)
#pragma unroll
                for (int g = 0; g < 4; ++g)
                    a0[g] = __builtin_amdgcn_mfma_f32_16x16x32_bf16(h0f, whh0[g][kk], a0[g], 0, 0, 0);
            if constexpr (D1)
#pragma unroll
                for (int g = 0; g < 4; ++g)
                    a1[g] = __builtin_amdgcn_mfma_f32_16x16x32_bf16(h0f, wih1[g][kk], a1[g], 0, 0, 0);
        }

        // L1-hh K-loop (independent of EW-L0 below -> scheduler co-issues)
        if constexpr (D1) {
#pragma unroll
            for (int kk = 0; kk < 4; ++kk) {
                const short8 h1f = *(const short8*)(r1 + kk * 512 + rdoff);
#pragma unroll
                for (int g = 0; g < 4; ++g)
                    a1[g] = __builtin_amdgcn_mfma_f32_16x16x32_bf16(h1f, whh1[g][kk], a1[g], 0, 0, 0);
            }
        }

        if constexpr (D0) {
#pragma unroll
            for (int rr = 0; rr < 2; ++rr) {
                const float iv = sig_(a0[0][rr]);
                const float fv = sig_(a0[1][rr]);
                const float gv = tanh_(a0[2][rr]);
                const float ov = sig_(a0[3][rr]);
                cf0[rr] = fv * cf0[rr] + iv * gv;
                w0[chunkbase + (4 * q + rr) * 8] = f2b(ov * tanh_(cf0[rr]));
            }
        }

        if constexpr (D1) {
#pragma unroll
            for (int rr = 0; rr < 2; ++rr) {
                const float iv = sig_(a1[0][rr]);
                const float fv = sig_(a1[1][rr]);
                const float gv = tanh_(a1[2][rr]);
                const float ov = sig_(a1[3][rr]);
                cf1[rr] = fv * cf1[rr] + iv * gv;
                const float hv = ov * tanh_(cf1[rr]);
                if constexpr (FIN) fout[rr * HDIM] = hv;
                else w1[chunkbase + (4 * q + rr) * 8] = f2b(hv);
            }
        }

        // lgkm-only barrier: h_t visible, but vmcnt (xg prefetch) stays in flight
        if constexpr (!FIN)
            asm volatile("s_waitcnt lgkmcnt(0)\n\ts_barrier" ::: "memory");
    };

    unsigned short* h0A = hbuf;
    unsigned short* h0B = hbuf + 2048;
    unsigned short* h1A = hbuf + 4096;
    unsigned short* h1B = hbuf + 6144;
    using T = Flag<true>; using F = Flag<false>;

    step(T{}, F{}, F{}, h0A, h0B, h1A, h1B, xgA, xgB);      // k=0: L0 only
#pragma unroll 1
    for (int k = 0; k < 255; ++k) {                          // k=1..510
        step(T{}, T{}, F{}, h0B, h0A, h1B, h1A, xgB, xgA);
        step(T{}, T{}, F{}, h0A, h0B, h1A, h1B, xgA, xgB);
    }
    step(T{}, T{}, F{}, h0B, h0A, h1B, h1A, xgB, xgA);      // k=511
    step(F{}, T{}, T{}, h0A, h0B, h1A, h1B, xgA, xgB);      // k=512: L1 only -> out
}

// ---- workspace layout (bytes) ----
//        0 : whh0_b 131072
//   131072 : wih1_b 131072
//   262144 : whh1_b 131072
//   393216 : bias1    2048
//   524288 : xg   134742016   ((S_LEN+2) t-slots: 2 pad slots for tail prefetch)
// total ~135.3 MB

extern "C" void kernel_launch(void* const* d_in, const int* in_sizes, int n_in,
                              void* d_out, int out_size, void* d_ws, size_t ws_size,
                              hipStream_t stream) {
    const float* x    = (const float*)d_in[0];
    const float* wih0 = (const float*)d_in[1];
    const float* whh0 = (const float*)d_in[2];
    const float* bih0 = (const float*)d_in[3];
    const float* bhh0 = (const float*)d_in[4];
    const float* wih1 = (const float*)d_in[5];
    const float* whh1 = (const float*)d_in[6];
    const float* bih1 = (const float*)d_in[7];
    const float* bhh1 = (const float*)d_in[8];

    char* ws = (char*)d_ws;
    unsigned short* whh0_b = (unsigned short*)(ws + 0);
    unsigned short* wih1_b = (unsigned short*)(ws + 131072);
    unsigned short* whh1_b = (unsigned short*)(ws + 262144);
    float*          bias1  = (float*)(ws + 393216);
    unsigned short* xgp    = (unsigned short*)(ws + 524288);

    conv_kernel<<<256, 256, 0, stream>>>(whh0, wih1, whh1, bih1, bhh1,
                                         whh0_b, wih1_b, whh1_b, bias1);
    xg_gemm<<<dim3(32, 16), 512, 0, stream>>>(x, wih0, bih0, bhh0, xgp);
    lstm_fused<<<32, 512, 0, stream>>>(whh0_b, wih1_b, whh1_b, bias1, xgp,
                                       (float*)d_out);
}

// Round 4
// 694.539 us; speedup vs baseline: 1.5234x; 1.5234x over previous
//
#include <hip/hip_runtime.h>
#include <cstdint>
#include <cstddef>

// LSTM B=256,S=512,C=64,H=128, 2 layers, gates i,f,g,o (torch order).
// Round 7: revert to round-5 phase-split structure (609 us; round-6 merge
// spilled: +16 co-live regs over the 256 cliff -> WRITE_SIZE 4992KB).
// New: 64 blocks x 4 batch rows (was 32 x 8):
//   - EW halves: 1 cell/lane/layer (rr=0 only) -> 20 trans/lane/step.
//   - A-frag redirect is 4-way broadcast (rred = r&~3): unique bytes per
//     ds_read_b128 drop 512B -> 256B (broadcast lanes free, m136).
//   - h writes halve (1 ds_write_b16/lane/layer); xg init load is b64.
//   - MFMA count/weights (192 regs, asm-pinned)/1 barrier per step unchanged.
//   - s_setprio(1) around MFMA clusters (T5; waves are phase-diverse).
// Valid tile rows: m&3==0 (batch row = m>>2). Tile rows 4b+1..3 are dups
// on the A side (redirect) and never-written garbage in the h tiles.
//
// MFMA 16x16x32 bf16 frags (verified rounds 1-6):
//   A[m=lane&15][k=(lane>>4)*8+j], B == W[n=lane&15][k] 16B row chunk,
//   D[m=4*(lane>>4)+reg][n=lane&15]

#define S_LEN 512
#define B_SZ  256
#define C_IN  64
#define HDIM  128
#define NBLK  64                     // recurrent blocks, 4 batch rows each
#define XG_TSTRIDE (64 * 512 * 4)    // shorts per timestep slot of xg (=131072)

using short4v = __attribute__((ext_vector_type(4))) short;   // 4 bf16
using short8  = __attribute__((ext_vector_type(8))) short;   // 8 bf16
using float4v = __attribute__((ext_vector_type(4))) float;

template<bool V> struct Flag { static constexpr bool value = V; };

__device__ __forceinline__ unsigned short f2b(float f) {
    union { float f; unsigned int u; } v; v.f = f;
    unsigned int u = v.u;
    return (unsigned short)((u + 0x7FFFu + ((u >> 16) & 1u)) >> 16);
}
__device__ __forceinline__ float b2f(unsigned short s) {
    union { unsigned int u; float f; } v; v.u = ((unsigned int)s) << 16;
    return v.f;
}
// lean activations: sigma = rcp(1+exp2(-x*log2e)), tanh = 1-2*rcp(1+exp2(2x*log2e))
__device__ __forceinline__ float sig_(float x) {
    return __builtin_amdgcn_rcpf(1.0f + __builtin_amdgcn_exp2f(x * -1.442695041f));
}
__device__ __forceinline__ float tanh_(float x) {
    return 1.0f - 2.0f * __builtin_amdgcn_rcpf(1.0f + __builtin_amdgcn_exp2f(x * 2.885390082f));
}
__device__ __forceinline__ short8 load8_f2b(const float* s) {
    const float4v f0 = *(const float4v*)s;
    const float4v f1 = *(const float4v*)(s + 4);
    short8 t;
#pragma unroll
    for (int e = 0; e < 4; ++e) {
        t[e]     = (short)f2b(f0[e]);
        t[e + 4] = (short)f2b(f1[e]);
    }
    return t;
}

// ---- weight conversion (fp32 -> bf16 B-frag-readable row-major) ----
__global__ void conv_kernel(const float* __restrict__ whh0,
                            const float* __restrict__ wih1, const float* __restrict__ whh1,
                            const float* __restrict__ bih1, const float* __restrict__ bhh1,
                            unsigned short* __restrict__ whh0_b, unsigned short* __restrict__ wih1_b,
                            unsigned short* __restrict__ whh1_b, float* __restrict__ bias1) {
    int i = blockIdx.x * blockDim.x + threadIdx.x;
    if (i < 4 * HDIM * HDIM) {
        whh0_b[i] = f2b(whh0[i]);
        wih1_b[i] = f2b(wih1[i]);
        whh1_b[i] = f2b(whh1[i]);
    }
    if (i < 4 * HDIM) bias1[i] = bih1[i] + bhh1[i];
}

// ---- hoisted L0 input GEMM: xg[t][blk][tid][4] = (x@Wih0^T + bih0 + bhh0)
//      for the lane's single valid row (m=4q, batch row q), packed so the
//      recurrent kernel's lane (same blk,tid mapping) loads its 4 acc-init
//      values as one 8B read.
__global__ __launch_bounds__(512, 2)
void xg_gemm(const float* __restrict__ x, const float* __restrict__ wih0,
             const float* __restrict__ bih0, const float* __restrict__ bhh0,
             unsigned short* __restrict__ xg) {
    const int tid = threadIdx.x;
    const int w = tid >> 6, L = tid & 63, q = L >> 4, r = L & 15;
    const int blk = blockIdx.x, tch = blockIdx.y;
    const int boff = blk * 4, j = w * 16 + r;
    const int rowload = r >> 2;      // tile row r carries batch row r>>2 (dups)

    short8 wf[4][2]; float bias_s[4];
#pragma unroll
    for (int g = 0; g < 4; ++g) {
        const int nrow = g * HDIM + j;
#pragma unroll
        for (int kk = 0; kk < 2; ++kk)
            wf[g][kk] = load8_f2b(wih0 + (size_t)nrow * C_IN + kk * 32 + q * 8);
        bias_s[g] = bih0[nrow] + bhh0[nrow];
    }

    const float* px = x + ((size_t)(boff + rowload) * S_LEN + (size_t)tch * 32) * C_IN + q * 8;
    unsigned short* po = xg + ((size_t)(tch * 32) * NBLK + blk) * 2048 + (size_t)tid * 4;

    for (int tt = 0; tt < 32; ++tt) {
        short8 xa[2];
#pragma unroll
        for (int kk = 0; kk < 2; ++kk) xa[kk] = load8_f2b(px + kk * 32);
        float4v a[4];
#pragma unroll
        for (int g = 0; g < 4; ++g) a[g] = (float4v){bias_s[g], 0.f, 0.f, 0.f};
#pragma unroll
        for (int kk = 0; kk < 2; ++kk)
#pragma unroll
            for (int g = 0; g < 4; ++g)
                a[g] = __builtin_amdgcn_mfma_f32_16x16x32_bf16(xa[kk], wf[g][kk], a[g], 0, 0, 0);
        short4v o;
#pragma unroll
        for (int g = 0; g < 4; ++g) o[g] = (short)f2b(a[g][0]);
        *(short4v*)po = o;
        px += C_IN;
        po += XG_TSTRIDE;
    }
}

// ---- fused 2-layer recurrence ----
__global__ __launch_bounds__(512, 2)
void lstm_fused(const unsigned short* __restrict__ whh0_b,
                const unsigned short* __restrict__ wih1_b,
                const unsigned short* __restrict__ whh1_b,
                const float* __restrict__ bias1,
                const unsigned short* __restrict__ xg,
                float* __restrict__ out) {
    // LDS: h0 double-buffer + h1 double-buffer, each 2048 shorts (16 rows x 128 cols)
    __shared__ __align__(16) unsigned short hbuf[4 * 2048];
    const int tid = threadIdx.x;
    const int w = tid >> 6, L = tid & 63, q = L >> 4, r = L & 15;
    const int blk = blockIdx.x;
    const int boff = blk * 4, j = w * 16 + r;

    // register/AGPR-resident weights: 48 B-frags = 192 regs, pinned vs remat
    short8 whh0[4][4], wih1[4][4], whh1[4][4];
    float b1s[4];
#pragma unroll
    for (int g = 0; g < 4; ++g) {
        const size_t nrow = (size_t)(g * HDIM + j);
#pragma unroll
        for (int kk = 0; kk < 4; ++kk) {
            whh0[g][kk] = *(const short8*)(whh0_b + nrow * HDIM + kk * 32 + q * 8);
            wih1[g][kk] = *(const short8*)(wih1_b + nrow * HDIM + kk * 32 + q * 8);
            whh1[g][kk] = *(const short8*)(whh1_b + nrow * HDIM + kk * 32 + q * 8);
        }
        b1s[g] = bias1[g * HDIM + j];
    }
#pragma unroll
    for (int g = 0; g < 4; ++g) {
        asm volatile("" : "+v"(whh0[g][0]), "+v"(whh0[g][1]), "+v"(whh0[g][2]), "+v"(whh0[g][3]));
        asm volatile("" : "+v"(wih1[g][0]), "+v"(wih1[g][1]), "+v"(wih1[g][2]), "+v"(wih1[g][3]));
        asm volatile("" : "+v"(whh1[g][0]), "+v"(whh1[g][1]), "+v"(whh1[g][2]), "+v"(whh1[g][3]));
    }

    for (int idx = tid; idx < 4 * 1024; idx += 512) ((unsigned int*)hbuf)[idx] = 0u;

    float cf0 = 0.f, cf1 = 0.f;
    // A-frag read: all lanes in an r-quad read the valid row (r&~3) -> 4-way
    // same-address broadcast, 256B unique per ds_read_b128.
    const int rred = r & ~3;
    const int rdoff = q * 128 + rred * 8;               // + kk*512 per K-chunk
    const int chunkbase = (j >> 3) * 128 + (j & 7);     // h write slot (col-chunk layout)
    const int wslot = chunkbase + (4 * q) * 8;          // this lane's h row (m=4q)
    float* fout = out + (size_t)(boff + q) * HDIM + j;

    const unsigned short* pxg = xg + (size_t)blk * 2048 + (size_t)tid * 4;
    short4v xgA = *(const short4v*)pxg;   // xg[t=0]
    pxg += XG_TSTRIDE;
    short4v xgB;

    __syncthreads();    // covers LDS zero + weight/xg load drain (once, cold)

    // iteration k: L0 h0_k (if D0) THEN L1 h1_{k-1} (if D1); both read only
    // previous-iteration buffers r0/r1, write w0/w1. One barrier at the end.
    auto step = [&](auto D0_, auto D1_, auto FIN_,
                    unsigned short* r0, unsigned short* w0,
                    unsigned short* r1, unsigned short* w1,
                    short4v& xc, short4v& xn) {
        constexpr bool D0  = decltype(D0_)::value;
        constexpr bool D1  = decltype(D1_)::value;
        constexpr bool FIN = decltype(FIN_)::value;

        if constexpr (!FIN) {            // prefetch next xg (vmcnt load, spans the barrier)
            xn = *(const short4v*)pxg;
            pxg += XG_TSTRIDE;
        }

        if constexpr (D0) {
            float4v a0[4];
#pragma unroll
            for (int g = 0; g < 4; ++g)
                a0[g] = (float4v){b2f((unsigned short)xc[g]), 0.f, 0.f, 0.f};
            __builtin_amdgcn_s_setprio(1);
#pragma unroll
            for (int kk = 0; kk < 4; ++kk) {
                const short8 h0f = *(const short8*)(r0 + kk * 512 + rdoff);
#pragma unroll
                for (int g = 0; g < 4; ++g)
                    a0[g] = __builtin_amdgcn_mfma_f32_16x16x32_bf16(h0f, whh0[g][kk], a0[g], 0, 0, 0);
            }
            __builtin_amdgcn_s_setprio(0);
            {
                const float iv = sig_(a0[0][0]);
                const float fv = sig_(a0[1][0]);
                const float gv = tanh_(a0[2][0]);
                const float ov = sig_(a0[3][0]);
                cf0 = fv * cf0 + iv * gv;
                w0[wslot] = f2b(ov * tanh_(cf0));
            }
        }

        if constexpr (D1) {
            float4v a1[4];
#pragma unroll
            for (int g = 0; g < 4; ++g) a1[g] = (float4v){b1s[g], 0.f, 0.f, 0.f};
            __builtin_amdgcn_s_setprio(1);
            // ih: input = h0_{k-1} (re-read from r0; broadcast-redirected rows)
#pragma unroll
            for (int kk = 0; kk < 4; ++kk) {
                const short8 hif = *(const short8*)(r0 + kk * 512 + rdoff);
#pragma unroll
                for (int g = 0; g < 4; ++g)
                    a1[g] = __builtin_amdgcn_mfma_f32_16x16x32_bf16(hif, wih1[g][kk], a1[g], 0, 0, 0);
            }
            // hh: h1_{k-2}
#pragma unroll
            for (int kk = 0; kk < 4; ++kk) {
                const short8 h1f = *(const short8*)(r1 + kk * 512 + rdoff);
#pragma unroll
                for (int g = 0; g < 4; ++g)
                    a1[g] = __builtin_amdgcn_mfma_f32_16x16x32_bf16(h1f, whh1[g][kk], a1[g], 0, 0, 0);
            }
            __builtin_amdgcn_s_setprio(0);
            {
                const float iv = sig_(a1[0][0]);
                const float fv = sig_(a1[1][0]);
                const float gv = tanh_(a1[2][0]);
                const float ov = sig_(a1[3][0]);
                cf1 = fv * cf1 + iv * gv;
                const float hv = ov * tanh_(cf1);
                if constexpr (FIN) fout[0] = hv;
                else w1[wslot] = f2b(hv);
            }
        }

        // lgkm-only barrier: h_t visible, but vmcnt (xg prefetch) stays in flight
        if constexpr (!FIN)
            asm volatile("s_waitcnt lgkmcnt(0)\n\ts_barrier" ::: "memory");
    };

    unsigned short* h0A = hbuf;
    unsigned short* h0B = hbuf + 2048;
    unsigned short* h1A = hbuf + 4096;
    unsigned short* h1B = hbuf + 6144;
    using T = Flag<true>; using F = Flag<false>;

    step(T{}, F{}, F{}, h0A, h0B, h1A, h1B, xgA, xgB);      // k=0: L0 only
#pragma unroll 1
    for (int k = 0; k < 255; ++k) {                          // k=1..510
        step(T{}, T{}, F{}, h0B, h0A, h1B, h1A, xgB, xgA);
        step(T{}, T{}, F{}, h0A, h0B, h1A, h1B, xgA, xgB);
    }
    step(T{}, T{}, F{}, h0B, h0A, h1B, h1A, xgB, xgA);      // k=511
    step(F{}, T{}, T{}, h0A, h0B, h1A, h1B, xgA, xgB);      // k=512: L1 only -> out
}

// ---- workspace layout (bytes) ----
//        0 : whh0_b 131072
//   131072 : wih1_b 131072
//   262144 : whh1_b 131072
//   393216 : bias1    2048
//   524288 : xg   134742016   ((S_LEN+2) t-slots: 2 pad slots for tail prefetch)
// total ~135.3 MB

extern "C" void kernel_launch(void* const* d_in, const int* in_sizes, int n_in,
                              void* d_out, int out_size, void* d_ws, size_t ws_size,
                              hipStream_t stream) {
    const float* x    = (const float*)d_in[0];
    const float* wih0 = (const float*)d_in[1];
    const float* whh0 = (const float*)d_in[2];
    const float* bih0 = (const float*)d_in[3];
    const float* bhh0 = (const float*)d_in[4];
    const float* wih1 = (const float*)d_in[5];
    const float* whh1 = (const float*)d_in[6];
    const float* bih1 = (const float*)d_in[7];
    const float* bhh1 = (const float*)d_in[8];

    char* ws = (char*)d_ws;
    unsigned short* whh0_b = (unsigned short*)(ws + 0);
    unsigned short* wih1_b = (unsigned short*)(ws + 131072);
    unsigned short* whh1_b = (unsigned short*)(ws + 262144);
    float*          bias1  = (float*)(ws + 393216);
    unsigned short* xgp    = (unsigned short*)(ws + 524288);

    conv_kernel<<<256, 256, 0, stream>>>(whh0, wih1, whh1, bih1, bhh1,
                                         whh0_b, wih1_b, whh1_b, bias1);
    xg_gemm<<<dim3(NBLK, 16), 512, 0, stream>>>(x, wih0, bih0, bhh0, xgp);
    lstm_fused<<<NBLK, 512, 0, stream>>>(whh0_b, wih1_b, whh1_b, bias1, xgp,
                                         (float*)d_out);
}